// Round 1
// baseline (422.535 us; speedup 1.0000x reference)
//
#include <hip/hip_runtime.h>
#include <hip/hip_bf16.h>
#include <math.h>

#define DDIM 32
#define KMIX 8

// ---------- prep: Gauss-Jordan inverse + logdet for K small matrices ----------
// One block (one wave, 64 threads) per mixture component. aug = [A | I] in LDS.
__global__ __launch_bounds__(64) void gmm_prep(const float* __restrict__ S,
                                               float* __restrict__ invS,
                                               float* __restrict__ logdetv)
{
    __shared__ float aug[DDIM][2 * DDIM];
    __shared__ int s_pr;
    __shared__ float s_ld;
    const int k = blockIdx.x;
    const int t = threadIdx.x;  // 0..63, single wave

    for (int r = 0; r < DDIM; ++r)
        aug[r][t] = (t < DDIM) ? S[k * DDIM * DDIM + r * DDIM + t]
                               : ((t - DDIM) == r ? 1.f : 0.f);
    if (t == 0) s_ld = 0.f;
    __syncthreads();

    for (int p = 0; p < DDIM; ++p) {
        if (t == 0) {  // partial pivot search (serial scan, 32 elems, negligible)
            int pr = p;
            float best = fabsf(aug[p][p]);
            for (int r = p + 1; r < DDIM; ++r) {
                float v = fabsf(aug[r][p]);
                if (v > best) { best = v; pr = r; }
            }
            s_pr = pr;
        }
        __syncthreads();
        const int pr = s_pr;
        if (pr != p) {  // swap rows p <-> pr, one column per thread
            float tmp = aug[p][t];
            aug[p][t] = aug[pr][t];
            aug[pr][t] = tmp;
        }
        __syncthreads();
        float piv = aug[p][p];
        if (t == 0) s_ld += logf(fabsf(piv));  // slogdet: log|det| = sum log|pivots|
        const float ip = 1.f / piv;
        aug[p][t] *= ip;
        __syncthreads();
        // elimination: single-wave block -> all lanes read f (ds broadcast) before
        // any lane writes the row (lockstep, program order), so no sync needed per row
        for (int r = 0; r < DDIM; ++r) {
            if (r == p) continue;
            const float f = aug[r][p];
            aug[r][t] -= f * aug[p][t];
        }
        __syncthreads();
    }

    for (int r = 0; r < DDIM; ++r)
        if (t >= DDIM) invS[k * DDIM * DDIM + r * DDIM + (t - DDIM)] = aug[r][t];
    if (t == 0) logdetv[k] = s_ld;
}

// ---------- main: per-row Mahalanobis quad form + softmax over K=8 ----------
__global__ __launch_bounds__(256) void gmm_main(const float* __restrict__ X,
                                                const float* __restrict__ mus,
                                                const float* __restrict__ phis,
                                                const float* __restrict__ invS,
                                                const float* __restrict__ logdetv,
                                                float* __restrict__ out, int N)
{
    // aff parking slots: stride 9 (coprime with 32 banks) -> conflict-free
    __shared__ float s_aff[256 * (KMIX + 1)];
    const int tid = threadIdx.x;
    const int n = blockIdx.x * 256 + tid;

    float x[DDIM];
    if (n < N) {
        const float4* X4 = (const float4*)(X + (size_t)n * DDIM);
#pragma unroll
        for (int j = 0; j < DDIM / 4; ++j) {
            float4 v = X4[j];
            x[4 * j + 0] = v.x; x[4 * j + 1] = v.y;
            x[4 * j + 2] = v.z; x[4 * j + 3] = v.w;
        }
    } else {
#pragma unroll
        for (int j = 0; j < DDIM; ++j) x[j] = 0.f;  // benign dummy work
    }

    const float log2pi = 1.8378770664093453f;

#pragma unroll 1  // keep k rolled: bounds code size; aff parked in LDS (no runtime reg-index)
    for (int k = 0; k < KMIX; ++k) {
        const float* __restrict__ A = invS + k * DDIM * DDIM;  // wave-uniform -> s_load
        const float* __restrict__ mu = mus + k * DDIM;         // wave-uniform -> s_load
        float diff[DDIM];
#pragma unroll
        for (int d = 0; d < DDIM; ++d) diff[d] = x[d] - mu[d];
        float quad = 0.f;
#pragma unroll
        for (int d = 0; d < DDIM; ++d) {
            float t = 0.f;
#pragma unroll
            for (int e = 0; e < DDIM; ++e) t = fmaf(A[d * DDIM + e], diff[e], t);
            quad = fmaf(diff[d], t, quad);
        }
        quad *= -0.5f;
        const float log_den = 0.5f * (DDIM * log2pi + logdetv[k]);
        const float aff = phis[k] * (quad - expf(log_den));
        s_aff[tid * (KMIX + 1) + k] = aff;
    }

    if (n >= N) return;

    float a[KMIX];
#pragma unroll
    for (int k = 0; k < KMIX; ++k) a[k] = s_aff[tid * (KMIX + 1) + k];

    float m = a[0];
#pragma unroll
    for (int k = 1; k < KMIX; ++k) m = fmaxf(m, a[k]);
    float p[KMIX];
    float s = 0.f;
#pragma unroll
    for (int k = 0; k < KMIX; ++k) { p[k] = expf(a[k] - m); s += p[k]; }
    const float inv = 1.f / s;

    float4* O4 = (float4*)(out + (size_t)n * KMIX);
    O4[0] = make_float4(p[0] * inv, p[1] * inv, p[2] * inv, p[3] * inv);
    O4[1] = make_float4(p[4] * inv, p[5] * inv, p[6] * inv, p[7] * inv);
}

extern "C" void kernel_launch(void* const* d_in, const int* in_sizes, int n_in,
                              void* d_out, int out_size, void* d_ws, size_t ws_size,
                              hipStream_t stream) {
    const float* X    = (const float*)d_in[0];
    const float* mus  = (const float*)d_in[1];
    const float* sig  = (const float*)d_in[2];
    const float* phis = (const float*)d_in[3];
    float* out = (float*)d_out;

    float* ws   = (float*)d_ws;
    float* invS = ws;                       // 8*32*32 floats
    float* ld   = ws + KMIX * DDIM * DDIM;  // 8 floats

    const int N = in_sizes[0] / DDIM;

    gmm_prep<<<KMIX, 64, 0, stream>>>(sig, invS, ld);

    const int block = 256;
    const int grid = (N + block - 1) / block;
    gmm_main<<<grid, block, 0, stream>>>(X, mus, phis, invS, ld, out, N);
}

// Round 2
// 156.304 us; speedup vs baseline: 2.7033x; 2.7033x over previous
//
#include <hip/hip_runtime.h>
#include <hip/hip_bf16.h>
#include <math.h>

#define DDIM 32
#define KMIX 8
#define TPW 5  // 16-row tiles per wave

typedef short bf16x8 __attribute__((ext_vector_type(8)));
typedef float f32x4 __attribute__((ext_vector_type(4)));

// ---------- prep: Gauss-Jordan inverse + logdet for K small matrices ----------
__global__ __launch_bounds__(64) void gmm_prep(const float* __restrict__ S,
                                               float* __restrict__ invS,
                                               float* __restrict__ logdetv)
{
    __shared__ float aug[DDIM][2 * DDIM];
    __shared__ int s_pr;
    __shared__ float s_ld;
    const int k = blockIdx.x;
    const int t = threadIdx.x;  // 0..63, single wave

    for (int r = 0; r < DDIM; ++r)
        aug[r][t] = (t < DDIM) ? S[k * DDIM * DDIM + r * DDIM + t]
                               : ((t - DDIM) == r ? 1.f : 0.f);
    if (t == 0) s_ld = 0.f;
    __syncthreads();

    for (int p = 0; p < DDIM; ++p) {
        if (t == 0) {
            int pr = p;
            float best = fabsf(aug[p][p]);
            for (int r = p + 1; r < DDIM; ++r) {
                float v = fabsf(aug[r][p]);
                if (v > best) { best = v; pr = r; }
            }
            s_pr = pr;
        }
        __syncthreads();
        const int pr = s_pr;
        if (pr != p) {
            float tmp = aug[p][t];
            aug[p][t] = aug[pr][t];
            aug[pr][t] = tmp;
        }
        __syncthreads();
        float piv = aug[p][p];
        if (t == 0) s_ld += logf(fabsf(piv));
        const float ip = 1.f / piv;
        aug[p][t] *= ip;
        __syncthreads();
        for (int r = 0; r < DDIM; ++r) {
            if (r == p) continue;
            const float f = aug[r][p];
            aug[r][t] -= f * aug[p][t];
        }
        __syncthreads();
    }

    for (int r = 0; r < DDIM; ++r)
        if (t >= DDIM) invS[k * DDIM * DDIM + r * DDIM + (t - DDIM)] = aug[r][t];
    if (t == 0) logdetv[k] = s_ld;
}

// ---------- prep2: bf16 W^T panel, A*mu vectors, folded affine constants ----
// diff'A diff = x'Ax - 2(A mu)'x + mu'A mu   (A symmetric)
// Wtg[(k*32+e)*32 + d] = A_k[d][e]   (bf16 RNE)  -> Y = X*W gives x'A columns
// amu[k][e] = (A_k mu_k)[e]          (fp32, used in the dot phase)
// aff = pa2[k]*(x'Ax - 2 amu.x) + pc[k],  pa2=-phi/2,
// pc[k] = -phi*( exp(log_den) + 0.5*mu'A mu ) ... since -0.5*phi*(q) - phi*eld
//   with q = x'Ax - 2amu.x + muAmu:  aff = pa2*(x'Ax - 2amu.x) + pa2*muAmu - phi*eld
__global__ void gmm_prep2(const float* __restrict__ invS, const float* __restrict__ ld,
                          const float* __restrict__ phis, const float* __restrict__ mus,
                          ushort* __restrict__ Wtg, float* __restrict__ amu,
                          float* __restrict__ pa2, float* __restrict__ pc)
{
    const int t = threadIdx.x;
    // amu: 8 k * 32 e = 256 values, one per thread
    {
        const int k = t >> 5, e = t & 31;
        float acc = 0.f;
        for (int d = 0; d < DDIM; ++d)
            acc = fmaf(invS[k * 1024 + e * 32 + d], mus[k * 32 + d], acc);  // (A mu)[e], A symm
        amu[t] = acc;
    }
    for (int i = t; i < KMIX * DDIM * DDIM; i += 256) {
        int k = i >> 10, e = (i >> 5) & 31, d = i & 31;
        float f = invS[k * 1024 + d * 32 + e];
        unsigned u = __builtin_bit_cast(unsigned, f);
        u = (u + 0x7FFFu + ((u >> 16) & 1u)) >> 16;  // RNE to bf16
        Wtg[i] = (ushort)u;
    }
    __syncthreads();
    if (t < KMIX) {
        float muAmu = 0.f;
        for (int e = 0; e < DDIM; ++e) muAmu = fmaf(amu[t * 32 + e], mus[t * 32 + e], muAmu);
        const float eld = expf(0.5f * (DDIM * 1.8378770664093453f + ld[t]));
        pa2[t] = -0.5f * phis[t];
        pc[t]  = -0.5f * phis[t] * muAmu - phis[t] * eld;
    }
}

// ---------- DPP 16-lane butterfly sum (pure VALU pipe) ----------------------
template <int CTRL>
__device__ __forceinline__ float dpp_add(float v) {
    int t = __builtin_amdgcn_update_dpp(0, __builtin_bit_cast(int, v), CTRL, 0xF, 0xF, true);
    return v + __builtin_bit_cast(float, t);
}
__device__ __forceinline__ float row16_sum(float v) {
    v = dpp_add<0xB1>(v);   // quad_perm [1,0,3,2]
    v = dpp_add<0x4E>(v);   // quad_perm [2,3,0,1]
    v = dpp_add<0x141>(v);  // row_half_mirror
    v = dpp_add<0x140>(v);  // row_mirror
    return v;
}
__device__ __forceinline__ float sel4(float a0, float a1, float a2, float a3, int r) {
    float b0 = (r & 1) ? a1 : a0;
    float b1 = (r & 1) ? a3 : a2;
    return (r & 2) ? b1 : b0;
}

// ---------- main ------------------------------------------------------------
__global__ __launch_bounds__(256) void gmm_main(
    const float* __restrict__ X, const ushort* __restrict__ Wtg,
    const float* __restrict__ amug, const float* __restrict__ pa2g,
    const float* __restrict__ pcg, float* __restrict__ out, int N)
{
    __shared__ float x_s[4][16][36];
    const int tid = threadIdx.x;
    const int lane = tid & 63;
    const int wid = tid >> 6;
    const int g = lane >> 4;
    const int c = lane & 15;

    bf16x8 wf0[KMIX], wf1[KMIX];
#pragma unroll
    for (int k = 0; k < KMIX; ++k) {
        wf0[k] = *(const bf16x8*)(Wtg + (size_t)((k * 32 + c) * 32) + g * 8);
        wf1[k] = *(const bf16x8*)(Wtg + (size_t)((k * 32 + 16 + c) * 32) + g * 8);
    }
    float pa2[KMIX], pc[KMIX];
#pragma unroll
    for (int k = 0; k < KMIX; ++k) { pa2[k] = pa2g[k]; pc[k] = pcg[k]; }
    // amu values needed by the dot phase: lane (g,c) multiplies Y[row][k*32+t*16+c],
    // so it needs amu[k][t*16+c] (uniform per 16-lane group -> scalar-ish loads)
    float am0[KMIX], am1[KMIX];
#pragma unroll
    for (int k = 0; k < KMIX; ++k) {
        am0[k] = amug[k * 32 + c];
        am1[k] = amug[k * 32 + 16 + c];
    }

    const int ntiles = N >> 4;
    const int tile0 = (blockIdx.x * 4 + wid) * TPW;
    const float* lp = X + (size_t)tile0 * 512 + c * 32 + g * 8;

    const int rl = (lane >> 2) & 3;
    const int orow = lane >> 2;
    const int osel = lane & 3;
    const f32x4 zro = {0.f, 0.f, 0.f, 0.f};

    float4 a0 = {0,0,0,0}, a1 = {0,0,0,0};
    if (tile0 < ntiles) { a0 = *(const float4*)lp; a1 = *(const float4*)(lp + 4); }

#pragma unroll
    for (int it = 0; it < TPW; ++it) {
        const int tile = tile0 + it;
        float4 b0 = a0, b1 = a1;
        if (it + 1 < TPW && tile + 1 < ntiles) {
            b0 = *(const float4*)(lp + 512);
            b1 = *(const float4*)(lp + 516);
        }
        if (tile < ntiles) {
            *(float4*)&x_s[wid][c][g * 8]     = a0;
            *(float4*)&x_s[wid][c][g * 8 + 4] = a1;
            int4 xi;
            xi.x = __builtin_amdgcn_perm(__builtin_bit_cast(unsigned, a0.y), __builtin_bit_cast(unsigned, a0.x), 0x07060302u);
            xi.y = __builtin_amdgcn_perm(__builtin_bit_cast(unsigned, a0.w), __builtin_bit_cast(unsigned, a0.z), 0x07060302u);
            xi.z = __builtin_amdgcn_perm(__builtin_bit_cast(unsigned, a1.y), __builtin_bit_cast(unsigned, a1.x), 0x07060302u);
            xi.w = __builtin_amdgcn_perm(__builtin_bit_cast(unsigned, a1.w), __builtin_bit_cast(unsigned, a1.z), 0x07060302u);
            const bf16x8 xf = __builtin_bit_cast(bf16x8, xi);

            float xr0[4], xr1[4];
#pragma unroll
            for (int r = 0; r < 4; ++r) {
                xr0[r] = x_s[wid][g * 4 + r][c];
                xr1[r] = x_s[wid][g * 4 + r][c + 16];
            }
            float ak[KMIX];
#pragma unroll
            for (int k = 0; k < KMIX; ++k) {
                f32x4 acc0 = __builtin_amdgcn_mfma_f32_16x16x32_bf16(xf, wf0[k], zro, 0, 0, 0);
                f32x4 acc1 = __builtin_amdgcn_mfma_f32_16x16x32_bf16(xf, wf1[k], zro, 0, 0, 0);
                // q = x'Ax - 2 amu.x  : per-lane partial over cols c, c+16
                float q0 = row16_sum((acc0[0] - 2.f * am0[k]) * xr0[0] + (acc1[0] - 2.f * am1[k]) * xr1[0]);
                float q1 = row16_sum((acc0[1] - 2.f * am0[k]) * xr0[1] + (acc1[1] - 2.f * am1[k]) * xr1[1]);
                float q2 = row16_sum((acc0[2] - 2.f * am0[k]) * xr0[2] + (acc1[2] - 2.f * am1[k]) * xr1[2]);
                float q3 = row16_sum((acc0[3] - 2.f * am0[k]) * xr0[3] + (acc1[3] - 2.f * am1[k]) * xr1[3]);
                ak[k] = fmaf(pa2[k], sel4(q0, q1, q2, q3, rl), pc[k]);
            }
            float m = ak[0];
#pragma unroll
            for (int k = 1; k < KMIX; ++k) m = fmaxf(m, ak[k]);
            float e[KMIX], s = 0.f;
#pragma unroll
            for (int k = 0; k < KMIX; ++k) { e[k] = __expf(ak[k] - m); s += e[k]; }
            const float inv = 1.f / s;
            float2 o;
            o.x = sel4(e[0], e[2], e[4], e[6], osel) * inv;
            o.y = sel4(e[1], e[3], e[5], e[7], osel) * inv;
            *(float2*)(out + (size_t)(tile * 16 + orow) * 8 + osel * 2) = o;
        }
        a0 = b0; a1 = b1;
        lp += 512;
    }
}

extern "C" void kernel_launch(void* const* d_in, const int* in_sizes, int n_in,
                              void* d_out, int out_size, void* d_ws, size_t ws_size,
                              hipStream_t stream) {
    const float* X    = (const float*)d_in[0];
    const float* mus  = (const float*)d_in[1];
    const float* sig  = (const float*)d_in[2];
    const float* phis = (const float*)d_in[3];
    float* out = (float*)d_out;

    float* ws   = (float*)d_ws;
    float* invS = ws;                    // 8192 f32
    float* ld   = ws + 8192;             // 8 f32
    float* pa2  = ws + 8200;             // 8 f32
    float* pc   = ws + 8208;             // 8 f32
    float* amu  = ws + 8216;             // 256 f32
    ushort* Wtg = (ushort*)(ws + 8472);  // 8192 bf16, byte off 33888 (16B-aligned)

    const int N = in_sizes[0] / DDIM;

    gmm_prep<<<KMIX, 64, 0, stream>>>(sig, invS, ld);
    gmm_prep2<<<1, 256, 0, stream>>>(invS, ld, phis, mus, Wtg, amu, pa2, pc);

    const int ntiles = N >> 4;
    const int grid = (ntiles + 4 * TPW - 1) / (4 * TPW);
    gmm_main<<<grid, 256, 0, stream>>>(X, Wtg, amu, pa2, pc, out, N);
}

// Round 3
// 73.269 us; speedup vs baseline: 5.7669x; 2.1333x over previous
//
#include <hip/hip_runtime.h>
#include <hip/hip_bf16.h>
#include <math.h>

#define DDIM 32
#define KMIX 8
#define TPW 5  // 16-row tiles per wave

typedef short bf16x8 __attribute__((ext_vector_type(8)));
typedef float f32x4 __attribute__((ext_vector_type(4)));

// ---------- prep (merged): Gauss-Jordan inverse (no pivoting; SPD), logdet,
// bf16 W^T panel, A*mu, folded affine constants. One block per mixture,
// 1024 threads: thread t owns aug[r][c] and aug[r][c+32], r=t>>5, c=t&31.
__global__ __launch_bounds__(1024) void gmm_prep(
    const float* __restrict__ S, const float* __restrict__ mus,
    const float* __restrict__ phis, ushort* __restrict__ Wtg,
    float* __restrict__ amu, float* __restrict__ pa2, float* __restrict__ pc)
{
    __shared__ float aug[DDIM][2 * DDIM + 2];  // stride 66: column reads 2-way (free)
    __shared__ float pivsave[DDIM];
    __shared__ float amuL[DDIM];
    __shared__ float logL[DDIM];
    const int k = blockIdx.x;
    const int t = threadIdx.x;
    const int r = t >> 5, c = t & 31;

    aug[r][c]      = S[k * 1024 + r * 32 + c];
    aug[r][c + 32] = (c == r) ? 1.f : 0.f;
    __syncthreads();

    for (int p = 0; p < DDIM; ++p) {
        // reads BEFORE barrier (values this step will overwrite)
        const float piv   = aug[p][p];     // broadcast
        const float f     = aug[r][p];     // column p: 2-way bank alias (free)
        const float prow  = aug[p][c];     // pivot row: broadcast per c
        const float prow2 = aug[p][c + 32];
        __syncthreads();
        const float ip = 1.f / piv;
        if (r == p) {
            aug[r][c]      = prow * ip;
            aug[r][c + 32] = prow2 * ip;
            if (c == 0) pivsave[p] = piv;
        } else {
            const float fi = f * ip;
            aug[r][c]      = fmaf(-fi, prow,  aug[r][c]);
            aug[r][c + 32] = fmaf(-fi, prow2, aug[r][c + 32]);
        }
        __syncthreads();
    }

    // inverse now in aug[.][32..63]
    if (t < DDIM) {
        float acc = 0.f;
        for (int d = 0; d < DDIM; ++d)
            acc = fmaf(aug[t][32 + d], mus[k * 32 + d], acc);  // (A^-1 mu)[t]
        amuL[t] = acc;
        amu[k * 32 + t] = acc;
        logL[t] = logf(fabsf(pivsave[t]));
    }
    __syncthreads();

    // Wtg[(k*32+e)*32 + d] = inv[d][e]  (bf16 RNE)
    {
        const int e = t >> 5, d = t & 31;
        float fv = aug[d][32 + e];
        unsigned u = __builtin_bit_cast(unsigned, fv);
        u = (u + 0x7FFFu + ((u >> 16) & 1u)) >> 16;
        Wtg[k * 1024 + e * 32 + d] = (ushort)u;
    }
    if (t == 0) {
        float ldet = 0.f, muAmu = 0.f;
        for (int i = 0; i < DDIM; ++i) {
            ldet += logL[i];
            muAmu = fmaf(amuL[i], mus[k * 32 + i], muAmu);
        }
        const float eld = expf(0.5f * (DDIM * 1.8378770664093453f + ldet));
        pa2[k] = -0.5f * phis[k];
        pc[k]  = -0.5f * phis[k] * muAmu - phis[k] * eld;
    }
}

// ---------- DPP 16-lane butterfly sum (pure VALU pipe) ----------------------
template <int CTRL>
__device__ __forceinline__ float dpp_add(float v) {
    int t = __builtin_amdgcn_update_dpp(0, __builtin_bit_cast(int, v), CTRL, 0xF, 0xF, true);
    return v + __builtin_bit_cast(float, t);
}
__device__ __forceinline__ float row16_sum(float v) {
    v = dpp_add<0xB1>(v);   // quad_perm [1,0,3,2]
    v = dpp_add<0x4E>(v);   // quad_perm [2,3,0,1]
    v = dpp_add<0x141>(v);  // row_half_mirror
    v = dpp_add<0x140>(v);  // row_mirror
    return v;
}
__device__ __forceinline__ float sel4(float a0, float a1, float a2, float a3, int r) {
    float b0 = (r & 1) ? a1 : a0;
    float b1 = (r & 1) ? a3 : a2;
    return (r & 2) ? b1 : b0;
}

// ---------- main ------------------------------------------------------------
__global__ __launch_bounds__(256) void gmm_main(
    const float* __restrict__ X, const ushort* __restrict__ Wtg,
    const float* __restrict__ amug, const float* __restrict__ pa2g,
    const float* __restrict__ pcg, float* __restrict__ out, int N)
{
    __shared__ float x_s[4][16][36];
    const int tid = threadIdx.x;
    const int lane = tid & 63;
    const int wid = tid >> 6;
    const int g = lane >> 4;
    const int c = lane & 15;

    bf16x8 wf0[KMIX], wf1[KMIX];
#pragma unroll
    for (int k = 0; k < KMIX; ++k) {
        wf0[k] = *(const bf16x8*)(Wtg + (size_t)((k * 32 + c) * 32) + g * 8);
        wf1[k] = *(const bf16x8*)(Wtg + (size_t)((k * 32 + 16 + c) * 32) + g * 8);
    }
    float pa2[KMIX], pc[KMIX];
#pragma unroll
    for (int k = 0; k < KMIX; ++k) { pa2[k] = pa2g[k]; pc[k] = pcg[k]; }
    float am0[KMIX], am1[KMIX];
#pragma unroll
    for (int k = 0; k < KMIX; ++k) {
        am0[k] = amug[k * 32 + c];
        am1[k] = amug[k * 32 + 16 + c];
    }

    const int ntiles = N >> 4;
    const int tile0 = (blockIdx.x * 4 + wid) * TPW;
    const float* lp = X + (size_t)tile0 * 512 + c * 32 + g * 8;

    const int rl = (lane >> 2) & 3;
    const int orow = lane >> 2;
    const int osel = lane & 3;
    const f32x4 zro = {0.f, 0.f, 0.f, 0.f};

    float4 a0 = {0,0,0,0}, a1 = {0,0,0,0};
    if (tile0 < ntiles) { a0 = *(const float4*)lp; a1 = *(const float4*)(lp + 4); }

#pragma unroll
    for (int it = 0; it < TPW; ++it) {
        const int tile = tile0 + it;
        float4 b0 = a0, b1 = a1;
        if (it + 1 < TPW && tile + 1 < ntiles) {
            b0 = *(const float4*)(lp + 512);
            b1 = *(const float4*)(lp + 516);
        }
        if (tile < ntiles) {
            *(float4*)&x_s[wid][c][g * 8]     = a0;
            *(float4*)&x_s[wid][c][g * 8 + 4] = a1;
            int4 xi;
            xi.x = __builtin_amdgcn_perm(__builtin_bit_cast(unsigned, a0.y), __builtin_bit_cast(unsigned, a0.x), 0x07060302u);
            xi.y = __builtin_amdgcn_perm(__builtin_bit_cast(unsigned, a0.w), __builtin_bit_cast(unsigned, a0.z), 0x07060302u);
            xi.z = __builtin_amdgcn_perm(__builtin_bit_cast(unsigned, a1.y), __builtin_bit_cast(unsigned, a1.x), 0x07060302u);
            xi.w = __builtin_amdgcn_perm(__builtin_bit_cast(unsigned, a1.w), __builtin_bit_cast(unsigned, a1.z), 0x07060302u);
            const bf16x8 xf = __builtin_bit_cast(bf16x8, xi);

            float xr0[4], xr1[4];
#pragma unroll
            for (int r = 0; r < 4; ++r) {
                xr0[r] = x_s[wid][g * 4 + r][c];
                xr1[r] = x_s[wid][g * 4 + r][c + 16];
            }
            float ak[KMIX];
#pragma unroll
            for (int k = 0; k < KMIX; ++k) {
                f32x4 acc0 = __builtin_amdgcn_mfma_f32_16x16x32_bf16(xf, wf0[k], zro, 0, 0, 0);
                f32x4 acc1 = __builtin_amdgcn_mfma_f32_16x16x32_bf16(xf, wf1[k], zro, 0, 0, 0);
                float q0 = row16_sum((acc0[0] - 2.f * am0[k]) * xr0[0] + (acc1[0] - 2.f * am1[k]) * xr1[0]);
                float q1 = row16_sum((acc0[1] - 2.f * am0[k]) * xr0[1] + (acc1[1] - 2.f * am1[k]) * xr1[1]);
                float q2 = row16_sum((acc0[2] - 2.f * am0[k]) * xr0[2] + (acc1[2] - 2.f * am1[k]) * xr1[2]);
                float q3 = row16_sum((acc0[3] - 2.f * am0[k]) * xr0[3] + (acc1[3] - 2.f * am1[k]) * xr1[3]);
                ak[k] = fmaf(pa2[k], sel4(q0, q1, q2, q3, rl), pc[k]);
            }
            float m = ak[0];
#pragma unroll
            for (int k = 1; k < KMIX; ++k) m = fmaxf(m, ak[k]);
            float e[KMIX], s = 0.f;
#pragma unroll
            for (int k = 0; k < KMIX; ++k) { e[k] = __expf(ak[k] - m); s += e[k]; }
            const float inv = 1.f / s;
            float2 o;
            o.x = sel4(e[0], e[2], e[4], e[6], osel) * inv;
            o.y = sel4(e[1], e[3], e[5], e[7], osel) * inv;
            *(float2*)(out + (size_t)(tile * 16 + orow) * 8 + osel * 2) = o;
        }
        a0 = b0; a1 = b1;
        lp += 512;
    }
}

extern "C" void kernel_launch(void* const* d_in, const int* in_sizes, int n_in,
                              void* d_out, int out_size, void* d_ws, size_t ws_size,
                              hipStream_t stream) {
    const float* X    = (const float*)d_in[0];
    const float* mus  = (const float*)d_in[1];
    const float* sig  = (const float*)d_in[2];
    const float* phis = (const float*)d_in[3];
    float* out = (float*)d_out;

    float* ws   = (float*)d_ws;
    float* pa2  = ws;                   // 8 f32
    float* pc   = ws + 8;               // 8 f32
    float* amu  = ws + 16;              // 256 f32
    ushort* Wtg = (ushort*)(ws + 272);  // 8192 bf16, byte off 1088 (16B-aligned)

    const int N = in_sizes[0] / DDIM;

    gmm_prep<<<KMIX, 1024, 0, stream>>>(sig, mus, phis, Wtg, amu, pa2, pc);

    const int ntiles = N >> 4;
    const int grid = (ntiles + 4 * TPW - 1) / (4 * TPW);
    gmm_main<<<grid, 256, 0, stream>>>(X, Wtg, amu, pa2, pc, out, N);
}

// Round 4
// 59.840 us; speedup vs baseline: 7.0611x; 1.2244x over previous
//
#include <hip/hip_runtime.h>
#include <hip/hip_bf16.h>
#include <math.h>

#define DDIM 32
#define KMIX 8
#define TPW 5  // 16-row tiles per wave

typedef short bf16x8 __attribute__((ext_vector_type(8)));
typedef float f32x4 __attribute__((ext_vector_type(4)));

// ---------- prep (merged): Gauss-Jordan inverse (no pivoting; SPD), logdet,
// bf16 W^T panel, A*mu, folded affine constants (pre-scaled by log2(e)).
__global__ __launch_bounds__(1024) void gmm_prep(
    const float* __restrict__ S, const float* __restrict__ mus,
    const float* __restrict__ phis, ushort* __restrict__ Wtg,
    float* __restrict__ amu, float* __restrict__ pa2, float* __restrict__ pc)
{
    __shared__ float aug[DDIM][2 * DDIM + 2];  // stride 66: column reads 2-way (free)
    __shared__ float pivsave[DDIM];
    __shared__ float amuL[DDIM];
    __shared__ float logL[DDIM];
    const int k = blockIdx.x;
    const int t = threadIdx.x;
    const int r = t >> 5, c = t & 31;

    aug[r][c]      = S[k * 1024 + r * 32 + c];
    aug[r][c + 32] = (c == r) ? 1.f : 0.f;
    __syncthreads();

    for (int p = 0; p < DDIM; ++p) {
        const float piv   = aug[p][p];
        const float f     = aug[r][p];
        const float prow  = aug[p][c];
        const float prow2 = aug[p][c + 32];
        __syncthreads();
        const float ip = 1.f / piv;
        if (r == p) {
            aug[r][c]      = prow * ip;
            aug[r][c + 32] = prow2 * ip;
            if (c == 0) pivsave[p] = piv;
        } else {
            const float fi = f * ip;
            aug[r][c]      = fmaf(-fi, prow,  aug[r][c]);
            aug[r][c + 32] = fmaf(-fi, prow2, aug[r][c + 32]);
        }
        __syncthreads();
    }

    if (t < DDIM) {
        float acc = 0.f;
        for (int d = 0; d < DDIM; ++d)
            acc = fmaf(aug[t][32 + d], mus[k * 32 + d], acc);  // (A^-1 mu)[t]
        amuL[t] = acc;
        amu[k * 32 + t] = acc;
        logL[t] = logf(fabsf(pivsave[t]));
    }
    __syncthreads();

    {
        const int e = t >> 5, d = t & 31;
        float fv = aug[d][32 + e];
        unsigned u = __builtin_bit_cast(unsigned, fv);
        u = (u + 0x7FFFu + ((u >> 16) & 1u)) >> 16;  // RNE to bf16
        Wtg[k * 1024 + e * 32 + d] = (ushort)u;
    }
    if (t == 0) {
        float ldet = 0.f, muAmu = 0.f;
        for (int i = 0; i < DDIM; ++i) {
            ldet += logL[i];
            muAmu = fmaf(amuL[i], mus[k * 32 + i], muAmu);
        }
        const float eld = expf(0.5f * (DDIM * 1.8378770664093453f + ldet));
        const float LOG2E = 1.4426950408889634f;
        pa2[k] = -0.5f * phis[k] * LOG2E;                              // log2-domain
        pc[k]  = (-0.5f * phis[k] * muAmu - phis[k] * eld) * LOG2E;    // log2-domain
    }
}

// ---------- DPP helpers (VALU pipe; compiler fuses mov_dpp+add -> v_add_f32_dpp)
template <int CTRL>
__device__ __forceinline__ float dpp_add(float v) {
    int t = __builtin_amdgcn_update_dpp(0, __builtin_bit_cast(int, v), CTRL, 0xF, 0xF, true);
    return v + __builtin_bit_cast(float, t);
}
__device__ __forceinline__ float sel4(float a0, float a1, float a2, float a3, int r) {
    float b0 = (r & 1) ? a1 : a0;
    float b1 = (r & 1) ? a3 : a2;
    return (r & 2) ? b1 : b0;
}

// ---------- main ------------------------------------------------------------
// Reduction: quad-allreduce (xor1,xor2) on all 4 D-regs, select by lane&3
// (each lane keeps a distinct row), then row_ror:4 + row_ror:8 finish the
// 16-lane sum. Lane (g,c) ends with q[row = g*4 + (c&3)] for all 8 k.
__global__ __launch_bounds__(256, 3) void gmm_main(
    const float* __restrict__ X, const ushort* __restrict__ Wtg,
    const float* __restrict__ amug, const float* __restrict__ pa2g,
    const float* __restrict__ pcg, float* __restrict__ out, int N)
{
    __shared__ float x_s[4][16][36];
    const int tid = threadIdx.x;
    const int lane = tid & 63;
    const int wid = tid >> 6;
    const int g = lane >> 4;
    const int c = lane & 15;

    bf16x8 wf0[KMIX], wf1[KMIX];
#pragma unroll
    for (int k = 0; k < KMIX; ++k) {
        wf0[k] = *(const bf16x8*)(Wtg + (size_t)((k * 32 + c) * 32) + g * 8);
        wf1[k] = *(const bf16x8*)(Wtg + (size_t)((k * 32 + 16 + c) * 32) + g * 8);
    }
    float pa2[KMIX], pc[KMIX];
#pragma unroll
    for (int k = 0; k < KMIX; ++k) { pa2[k] = pa2g[k]; pc[k] = pcg[k]; }
    float n2am0[KMIX], n2am1[KMIX];
#pragma unroll
    for (int k = 0; k < KMIX; ++k) {
        n2am0[k] = -2.f * amug[k * 32 + c];
        n2am1[k] = -2.f * amug[k * 32 + 16 + c];
    }

    const int ntiles = N >> 4;
    const int tile0 = (blockIdx.x * 4 + wid) * TPW;
    const float* lp = X + (size_t)tile0 * 512 + c * 32 + g * 8;

    const int orow = ((lane >> 4) << 2) | (lane & 3);  // row this lane outputs
    const int osel = (lane >> 2) & 3;                  // k-pair this lane outputs
    const int rsel = lane & 3;                         // row selected after quad-allreduce
    const f32x4 zro = {0.f, 0.f, 0.f, 0.f};

    float4 a0 = {0,0,0,0}, a1 = {0,0,0,0};
    if (tile0 < ntiles) { a0 = *(const float4*)lp; a1 = *(const float4*)(lp + 4); }

#pragma unroll
    for (int it = 0; it < TPW; ++it) {
        const int tile = tile0 + it;
        float4 b0 = a0, b1 = a1;
        if (it + 1 < TPW && tile + 1 < ntiles) {
            b0 = *(const float4*)(lp + 512);
            b1 = *(const float4*)(lp + 516);
        }
        if (tile < ntiles) {
            *(float4*)&x_s[wid][c][g * 8]     = a0;
            *(float4*)&x_s[wid][c][g * 8 + 4] = a1;
            int4 xi;
            xi.x = __builtin_amdgcn_perm(__builtin_bit_cast(unsigned, a0.y), __builtin_bit_cast(unsigned, a0.x), 0x07060302u);
            xi.y = __builtin_amdgcn_perm(__builtin_bit_cast(unsigned, a0.w), __builtin_bit_cast(unsigned, a0.z), 0x07060302u);
            xi.z = __builtin_amdgcn_perm(__builtin_bit_cast(unsigned, a1.y), __builtin_bit_cast(unsigned, a1.x), 0x07060302u);
            xi.w = __builtin_amdgcn_perm(__builtin_bit_cast(unsigned, a1.w), __builtin_bit_cast(unsigned, a1.z), 0x07060302u);
            const bf16x8 xf = __builtin_bit_cast(bf16x8, xi);

            float xr0[4], xr1[4];
#pragma unroll
            for (int r = 0; r < 4; ++r) {
                xr0[r] = x_s[wid][g * 4 + r][c];
                xr1[r] = x_s[wid][g * 4 + r][c + 16];
            }
            float ak[KMIX];
#pragma unroll
            for (int k = 0; k < KMIX; ++k) {
                f32x4 acc0 = __builtin_amdgcn_mfma_f32_16x16x32_bf16(xf, wf0[k], zro, 0, 0, 0);
                f32x4 acc1 = __builtin_amdgcn_mfma_f32_16x16x32_bf16(xf, wf1[k], zro, 0, 0, 0);
                float r0 = (acc0[0] + n2am0[k]) * xr0[0] + (acc1[0] + n2am1[k]) * xr1[0];
                float r1 = (acc0[1] + n2am0[k]) * xr0[1] + (acc1[1] + n2am1[k]) * xr1[1];
                float r2 = (acc0[2] + n2am0[k]) * xr0[2] + (acc1[2] + n2am1[k]) * xr1[2];
                float r3 = (acc0[3] + n2am0[k]) * xr0[3] + (acc1[3] + n2am1[k]) * xr1[3];
                r0 = dpp_add<0xB1>(r0); r0 = dpp_add<0x4E>(r0);  // quad allreduce
                r1 = dpp_add<0xB1>(r1); r1 = dpp_add<0x4E>(r1);
                r2 = dpp_add<0xB1>(r2); r2 = dpp_add<0x4E>(r2);
                r3 = dpp_add<0xB1>(r3); r3 = dpp_add<0x4E>(r3);
                float v = sel4(r0, r1, r2, r3, rsel);            // lane keeps row g*4+(c&3)
                v = dpp_add<0x124>(v);                           // row_ror:4  (+quad c^..)
                v = dpp_add<0x128>(v);                           // row_ror:8
                ak[k] = fmaf(pa2[k], v, pc[k]);
            }
            float m = ak[0];
#pragma unroll
            for (int k = 1; k < KMIX; ++k) m = fmaxf(m, ak[k]);
            float e[KMIX], s = 0.f;
#pragma unroll
            for (int k = 0; k < KMIX; ++k) { e[k] = __builtin_amdgcn_exp2f(ak[k] - m); s += e[k]; }
            const float inv = 1.f / s;
            float2 o;
            o.x = sel4(e[0], e[2], e[4], e[6], osel) * inv;
            o.y = sel4(e[1], e[3], e[5], e[7], osel) * inv;
            *(float2*)(out + (size_t)(tile * 16 + orow) * 8 + osel * 2) = o;
        }
        a0 = b0; a1 = b1;
        lp += 512;
    }
}

extern "C" void kernel_launch(void* const* d_in, const int* in_sizes, int n_in,
                              void* d_out, int out_size, void* d_ws, size_t ws_size,
                              hipStream_t stream) {
    const float* X    = (const float*)d_in[0];
    const float* mus  = (const float*)d_in[1];
    const float* sig  = (const float*)d_in[2];
    const float* phis = (const float*)d_in[3];
    float* out = (float*)d_out;

    float* ws   = (float*)d_ws;
    float* pa2  = ws;                   // 8 f32
    float* pc   = ws + 8;               // 8 f32
    float* amu  = ws + 16;              // 256 f32
    ushort* Wtg = (ushort*)(ws + 272);  // 8192 bf16, byte off 1088 (16B-aligned)

    const int N = in_sizes[0] / DDIM;

    gmm_prep<<<KMIX, 1024, 0, stream>>>(sig, mus, phis, Wtg, amu, pa2, pc);

    const int ntiles = N >> 4;
    const int grid = (ntiles + 4 * TPW - 1) / (4 * TPW);
    gmm_main<<<grid, 256, 0, stream>>>(X, Wtg, amu, pa2, pc, out, N);
}